// Round 4
// baseline (42.692 us; speedup 1.0000x reference)
//
#include <hip/hip_runtime.h>

#define NQ 14
#define DIM (1 << NQ)       // 16384
#define NT 1024

typedef float __attribute__((ext_vector_type(2))) f2;   // packed (re,im)

__device__ __forceinline__ f2 pkfma(f2 a, f2 b, f2 c) {
  return __builtin_elementwise_fma(a, b, c);            // -> v_pk_fma_f32
}
__device__ __forceinline__ f2 sp(float x) { f2 r; r.x = x; r.y = x; return r; }

__device__ __forceinline__ f2 cmul(f2 a, f2 b) {
  f2 r; r.x = a.x * b.x - a.y * b.y; r.y = a.x * b.y + a.y * b.x; return r;
}

// RY on local bit K of a 16-element register subcube (compile-time indices only)
template<int K>
__device__ __forceinline__ void apply_ry(f2* v, float c, float s) {
  const f2 vc = sp(c), vs = sp(s), vsn = sp(-s);
#pragma unroll
  for (int m = 0; m < 8; ++m) {
    const int j0 = ((m >> K) << (K + 1)) | (m & ((1 << K) - 1));
    const int j1 = j0 | (1 << K);
    const f2 a0 = v[j0], a1 = v[j1];
    v[j0] = pkfma(a1, vsn, a0 * vc);
    v[j1] = pkfma(a0, vs,  a1 * vc);
  }
}

// <X> partial over local bit K
template<int K>
__device__ __forceinline__ float expv(const f2* v) {
  f2 acc = sp(0.f);
#pragma unroll
  for (int m = 0; m < 8; ++m) {
    const int j0 = ((m >> K) << (K + 1)) | (m & ((1 << K) - 1));
    const int j1 = j0 | (1 << K);
    acc = pkfma(v[j0], v[j1], acc);
  }
  return acc.x + acc.y;
}

// DPP lane butterflies: 0xB1 = xor lane-bit0, 0x4E = xor lane-bit1, 0x128 (row_ror:8) = xor lane-bit3
template<int CTRL>
__device__ __forceinline__ float dppf(float x) {
  return __int_as_float(__builtin_amdgcn_mov_dpp(__float_as_int(x), CTRL, 0xF, 0xF, true));
}

template<int CTRL>
__device__ __forceinline__ void dpp_ry(f2* v, float c, float se) {
  const f2 vc = sp(c), vse = sp(se);
#pragma unroll
  for (int j = 0; j < 16; ++j) {
    f2 p; p.x = dppf<CTRL>(v[j].x); p.y = dppf<CTRL>(v[j].y);
    v[j] = pkfma(p, vse, v[j] * vc);
  }
}

template<int CTRL>
__device__ __forceinline__ float dpp_expv(const f2* v) {
  f2 acc = sp(0.f);
#pragma unroll
  for (int j = 0; j < 16; ++j) {
    f2 p; p.x = dppf<CTRL>(v[j].x); p.y = dppf<CTRL>(v[j].y);
    acc = pkfma(v[j], p, acc);
  }
  return acc.x + acc.y;
}

__device__ __forceinline__ void wave_reduce_atomic(float val, float* dst) {
#pragma unroll
  for (int off = 32; off; off >>= 1) val += __shfl_down(val, off);
  if ((threadIdx.x & 63) == 0) atomicAdd(dst, val);
}

// per-wire 2-vector u = RY(q0) * RX(n) * RY(n) |0>
__device__ __forceinline__ void wire_u(float nz, float q0, f2& u0, f2& u1) {
  float sn, cn, sy, cy;
  __sincosf(0.5f * nz, &sn, &cn);
  __sincosf(0.5f * q0, &sy, &cy);
  const float cc = cn * cn, ss = sn * sn, cs = cn * sn;
  u0.x = cy * cc - sy * cs;  u0.y = sy * cs - cy * ss;
  u1.x = sy * cc + cy * cs;  u1.y = -sy * ss - cy * cs;
}

// ---- CZ ladder sign: parity(i & (i>>1)) ----
// Layout A: i = (t<<4)|m ; bits 0-3 = m, 4-9 = lane, 10-13 = wave
__device__ __forceinline__ void czA(f2* v, int l, int w) {
  const int base = (__popc(l & (l >> 1)) + __popc(w & (w >> 1)) + (((l >> 5) & 1) & (w & 1))) & 1;
  const int l0 = l & 1;
  const float f0 = base ? -1.f : 1.f;
  const float f1 = (base ^ l0) ? -1.f : 1.f;
#pragma unroll
  for (int m = 0; m < 16; ++m) {
    const bool ct = __popc(m & (m >> 1)) & 1;      // compile-time
    const float f = (m & 8) ? f1 : f0;
    v[m] = v[m] * sp(ct ? -f : f);
  }
}
// Layout B: bits 0-3=w, 4=l5, 5=l4, 6=l3, 7=l2, 8=l0, 9=l1, 10-13=m
__device__ __forceinline__ void czB(f2* v, int l, int w) {
  const int l0 = l & 1, l1 = (l >> 1) & 1, l2 = (l >> 2) & 1,
            l3 = (l >> 3) & 1, l4 = (l >> 4) & 1, l5 = (l >> 5) & 1;
  const int base = (__popc(w & (w >> 1)) + (((w >> 3) & 1) & l5) + (l5 & l4) +
                    (l4 & l3) + (l3 & l2) + (l2 & l0) + (l0 & l1)) & 1;
  const float f0 = base ? -1.f : 1.f;
  const float f1 = (base ^ l1) ? -1.f : 1.f;
#pragma unroll
  for (int m = 0; m < 16; ++m) {
    const bool ct = __popc(m & (m >> 1)) & 1;      // compile-time
    const float f = (m & 1) ? f1 : f0;
    v[m] = v[m] * sp(ct ? -f : f);
  }
}

// ---- gate groups ----
// A: reg bits 0-3 -> wires 13,12,11,10; lane bit0 -> wire9, bit1 -> wire8, bit3 -> wire6
__device__ __forceinline__ void gatesA(f2* v, const f2* csTab, int layer, int l) {
  const f2* cs = csTab + (layer - 1) * NQ;
  apply_ry<0>(v, cs[13].x, cs[13].y);
  apply_ry<1>(v, cs[12].x, cs[12].y);
  apply_ry<2>(v, cs[11].x, cs[11].y);
  apply_ry<3>(v, cs[10].x, cs[10].y);
  const f2 c9 = cs[9], c8 = cs[8], c6 = cs[6];
  dpp_ry<0xB1>(v, c9.x, (l & 1) ? c9.y : -c9.y);
  dpp_ry<0x4E>(v, c8.x, (l & 2) ? c8.y : -c8.y);
  dpp_ry<0x128>(v, c6.x, (l & 8) ? c6.y : -c6.y);
}
// B: reg bits 0-3 -> wires 3,2,1,0; lane bit0 -> wire5, bit1 -> wire4, bit3 -> wire7
__device__ __forceinline__ void gatesB(f2* v, const f2* csTab, int layer, int l) {
  const f2* cs = csTab + (layer - 1) * NQ;
  apply_ry<0>(v, cs[3].x, cs[3].y);
  apply_ry<1>(v, cs[2].x, cs[2].y);
  apply_ry<2>(v, cs[1].x, cs[1].y);
  apply_ry<3>(v, cs[0].x, cs[0].y);
  const f2 c5 = cs[5], c4 = cs[4], c7 = cs[7];
  dpp_ry<0xB1>(v, c5.x, (l & 1) ? c5.y : -c5.y);
  dpp_ry<0x4E>(v, c4.x, (l & 2) ? c4.y : -c4.y);
  dpp_ry<0x128>(v, c7.x, (l & 8) ? c7.y : -c7.y);
}

__global__ __launch_bounds__(NT, 4) void qsim_kernel(
    const float* __restrict__ noise, const float* __restrict__ qp,
    float* __restrict__ out) {
  __shared__ f2 st[DIM];            // 128 KiB, swizzled: phys = i ^ ((i>>4)&15) ^ ((i>>8)&3)
  __shared__ f2 csTab[5 * NQ];      // layers 1..5: (cos, sin) per wire
  __shared__ f2 uTab[NQ][2];        // encoding+layer0 per-wire 2-vectors
  __shared__ float exps[NQ];
  const int b = blockIdx.x;
  const int t = threadIdx.x;
  const int l = t & 63, w = t >> 6;

  // ---- one-time per-block tables ----
  if (t < 5 * NQ) {
    float s, c; __sincosf(0.5f * qp[NQ + t], &s, &c);
    f2 r; r.x = c; r.y = s; csTab[t] = r;
  }
  if (t < NQ) {
    exps[t] = 0.f;
    f2 u0, u1; wire_u(noise[b * NQ + t], qp[t], u0, u1);
    uTab[t][0] = u0; uTab[t][1] = u1;
  }

  // ---- addresses (f2 indices) ----
  // Layout A: amp i=(t<<4)|m -> slot addr = baseA ^ m
  const int baseA = (t << 4) | ((l & 15) ^ ((l >> 4) & 3));
  // Layout B: amp i=(m<<10)|(l1<<9)|(l0<<8)|(l2<<7)|(l3<<6)|(l4<<5)|(l5<<4)|w -> addr = baseB ^ (m<<10)
  const int l0 = l & 1, l1 = (l >> 1) & 1, l2 = (l >> 2) & 1,
            l3 = (l >> 3) & 1, l4 = (l >> 4) & 1, l5 = (l >> 5) & 1;
  const int baseB = (l1 << 9) | (l0 << 8) | (l2 << 7) | (l3 << 6) | (l4 << 5) | (l5 << 4)
                  | (w ^ (l5 | (l4 << 1) | (l3 << 2) | (l2 << 3)) ^ (l0 | (l1 << 1)));
  __syncthreads();

  // ---- product state: encoding + layer-0 RY on all 14 wires, pure registers ----
  f2 v[16];
  {
    f2 h; h.x = 1.f; h.y = 0.f;        // thread bit p = global bit 4+p = wire 9-p
#pragma unroll
    for (int p = 0; p < 10; ++p)
      h = cmul(h, uTab[9 - p][(t >> p) & 1]);
    v[0] = uTab[13][0]; v[1] = uTab[13][1];
#define BSTEP(P, WIRE)                                                      \
    {                                                                       \
      const f2 u0 = uTab[WIRE][0], u1 = uTab[WIRE][1];                      \
      _Pragma("unroll")                                                     \
      for (int jj = 0; jj < (1 << (P)); ++jj) {                             \
        v[jj | (1 << (P))] = cmul(v[jj], u1);                               \
        v[jj] = cmul(v[jj], u0);                                            \
      }                                                                     \
    }
    BSTEP(1, 12) BSTEP(2, 11) BSTEP(3, 10)
#undef BSTEP
#pragma unroll
    for (int m = 0; m < 16; ++m) v[m] = cmul(v[m], h);
  }
  czA(v, l, w);               // CZ of layer 0
  gatesA(v, csTab, 1, l);     // layer-1 gates on group-A wires, in registers
#pragma unroll
  for (int m = 0; m < 16; ++m) st[baseA ^ m] = v[m];
  __syncthreads();

  // P1 [B]: B(1) + CZ(1) + B(2)
#pragma unroll
  for (int m = 0; m < 16; ++m) v[m] = st[baseB ^ (m << 10)];
  gatesB(v, csTab, 1, l); czB(v, l, w); gatesB(v, csTab, 2, l);
#pragma unroll
  for (int m = 0; m < 16; ++m) st[baseB ^ (m << 10)] = v[m];
  __syncthreads();

  // P2 [A]: A(2) + CZ(2) + A(3)
#pragma unroll
  for (int m = 0; m < 16; ++m) v[m] = st[baseA ^ m];
  gatesA(v, csTab, 2, l); czA(v, l, w); gatesA(v, csTab, 3, l);
#pragma unroll
  for (int m = 0; m < 16; ++m) st[baseA ^ m] = v[m];
  __syncthreads();

  // P3 [B]: B(3) + CZ(3) + B(4)
#pragma unroll
  for (int m = 0; m < 16; ++m) v[m] = st[baseB ^ (m << 10)];
  gatesB(v, csTab, 3, l); czB(v, l, w); gatesB(v, csTab, 4, l);
#pragma unroll
  for (int m = 0; m < 16; ++m) st[baseB ^ (m << 10)] = v[m];
  __syncthreads();

  // P4 [A]: A(4) + CZ(4) + A(5)
#pragma unroll
  for (int m = 0; m < 16; ++m) v[m] = st[baseA ^ m];
  gatesA(v, csTab, 4, l); czA(v, l, w); gatesA(v, csTab, 5, l);
#pragma unroll
  for (int m = 0; m < 16; ++m) st[baseA ^ m] = v[m];
  __syncthreads();

  // P5 [B]: B(5) + CZ(5) + <X> for group-B wires {0,1,2,3,4,5,7}, write final state
#pragma unroll
  for (int m = 0; m < 16; ++m) v[m] = st[baseB ^ (m << 10)];
  gatesB(v, csTab, 5, l); czB(v, l, w);
  wave_reduce_atomic(expv<0>(v), &exps[3]);
  wave_reduce_atomic(expv<1>(v), &exps[2]);
  wave_reduce_atomic(expv<2>(v), &exps[1]);
  wave_reduce_atomic(expv<3>(v), &exps[0]);
  wave_reduce_atomic(dpp_expv<0xB1>(v), &exps[5]);
  wave_reduce_atomic(dpp_expv<0x4E>(v), &exps[4]);
  wave_reduce_atomic(dpp_expv<0x128>(v), &exps[7]);
#pragma unroll
  for (int m = 0; m < 16; ++m) st[baseB ^ (m << 10)] = v[m];
  __syncthreads();

  // P6 [A, read-only]: <X> for group-A wires {6,8,9,10,11,12,13}
#pragma unroll
  for (int m = 0; m < 16; ++m) v[m] = st[baseA ^ m];
  wave_reduce_atomic(expv<0>(v), &exps[13]);
  wave_reduce_atomic(expv<1>(v), &exps[12]);
  wave_reduce_atomic(expv<2>(v), &exps[11]);
  wave_reduce_atomic(expv<3>(v), &exps[10]);
  wave_reduce_atomic(dpp_expv<0xB1>(v), &exps[9]);
  wave_reduce_atomic(dpp_expv<0x4E>(v), &exps[8]);
  wave_reduce_atomic(dpp_expv<0x128>(v), &exps[6]);
  __syncthreads();

  if (t < NQ) {
    // reg-pair wires hold S (x2); DPP wires hold 2S already (pairs double-counted)
    const float f = (t >= 4 && t <= 9) ? 1.f : 2.f;
    out[b * NQ + t] = f * exps[t];
  }
}

extern "C" void kernel_launch(void* const* d_in, const int* in_sizes, int n_in,
                              void* d_out, int out_size, void* d_ws, size_t ws_size,
                              hipStream_t stream) {
  const float* noise = (const float*)d_in[0];  // [64, 14]
  const float* qp    = (const float*)d_in[1];  // [6, 14]
  float* out = (float*)d_out;                  // [64, 14]
  qsim_kernel<<<64, NT, 0, stream>>>(noise, qp, out);
}